// Round 15
// baseline (479.113 us; speedup 1.0000x reference)
//
#include <hip/hip_runtime.h>
#include <hip/hip_bf16.h>

#define B_  256
#define N_  343
#define C_  192
#define H_  6
#define D_  32
#define NW_ 32
#define NN_ (N_*N_)     /* 117649 */
#define TROWS 2197
#define NP_ 352                    /* padded N */
#define PLANE (NP_*NP_)            /* 123904 u16 per plane */

typedef unsigned int  uint32;
typedef unsigned short u16;
typedef __attribute__((ext_vector_type(8))) short bf16x8;
typedef __attribute__((ext_vector_type(4))) float f32x4;

union frag8 { uint4 u4; bf16x8 h8; short s[8]; };

__device__ __forceinline__ float bf2f(u16 u){
  union { uint32 u; float f; } v; v.u = ((uint32)u) << 16; return v.f;
}
__device__ __forceinline__ u16 f2bf(float f){
  union { float f; uint32 u; } v; v.f = f;
  uint32 u = v.u;
  return (u16)((u + 0x7FFFu + ((u >> 16) & 1u)) >> 16);  // RNE
}

// Deterministic dtype sniff (fp32 vs bf16 input world).
__device__ __forceinline__ bool detect_f32(const uint32* w){
  int c = 0;
  #pragma unroll
  for (int u = 0; u < 32; u++){
    int e = (w[u*37] >> 7) & 0xFF;
    c += (e > 150);
  }
  return c >= 3;
}
__device__ __forceinline__ float ldf(const void* p, size_t i, bool f32){
  return f32 ? ((const float*)p)[i] : bf2f(((const u16*)p)[i]);
}
__device__ __forceinline__ void stf(void* p, size_t i, float v, bool f32){
  if (f32) ((float*)p)[i] = v;
  else     ((u16*)p)[i]   = f2bf(v);
}

// packed-plane column decode: packed p = jc*32 + q*8 + half*4 + r  ->  source j
__device__ __forceinline__ int pm_srcj(int p){
  int jc = p >> 5, wi = p & 31;
  return (jc << 5) + ((wi >> 2) & 1)*16 + (wi >> 3)*4 + (wi & 3);
}

// 8 bf16 row-chunk load (zero-pad beyond N_ rows)
__device__ __forceinline__ uint4 ld_row8(const void* __restrict__ src, bool F32,
                                         int b, int grow, int col){
  if (grow >= N_) return make_uint4(0,0,0,0);
  size_t g = ((size_t)b*N_ + grow)*C_ + col;
  if (F32){
    const float* gp = (const float*)src + g;
    float4 f0 = *(const float4*)gp, f1 = *(const float4*)(gp + 4);
    frag8 fv;
    fv.s[0]=(short)f2bf(f0.x); fv.s[1]=(short)f2bf(f0.y);
    fv.s[2]=(short)f2bf(f0.z); fv.s[3]=(short)f2bf(f0.w);
    fv.s[4]=(short)f2bf(f1.x); fv.s[5]=(short)f2bf(f1.y);
    fv.s[6]=(short)f2bf(f1.z); fv.s[7]=(short)f2bf(f1.w);
    return fv.u4;
  }
  return *(const uint4*)((const u16*)src + g);
}

/* ====================== big-ws path kernels ====================== */

#define PM_PLANES (H_ + NW_)   /* 38: bp 6 planes + msp 32 planes */
#define PM_CHUNKS ((size_t)PM_PLANES*PLANE/8)   /* 588544 */
#define PM_BLKS   ((int)((PM_CHUNKS + 511)/512))  /* 1150 */

// Fat kernel: blocks [0,256) = KV GEMM; blocks [256,...) = packed split-plane
// prep (proven non-interfering, R13/R14). K now stored LINEAR [352][32] and
// V^T LINEAR [32][352] (no LDS swizzle needed — attn2 reads from L2 directly).
__global__ __launch_bounds__(512, 2) void kv_pm(
    const void* __restrict__ skip, const void* __restrict__ kv_w,
    const void* __restrict__ kv_b, u16* __restrict__ kvws,
    const int* __restrict__ rel, const void* __restrict__ table,
    const void* __restrict__ mask, u16* __restrict__ pm){
  __shared__ __align__(16) u16 sk[32*200];   // 12.8 KB (kv path only)
  const bool F32 = detect_f32((const uint32*)skip);
  const int bx = blockIdx.x;
  const int t = threadIdx.x;

  if (bx >= B_){
    // ---- pm path (packed columns) ----
    const float LOG2E = 1.4426950408889634f;
    size_t chunk = (size_t)(bx - B_)*512 + t;
    if (chunk >= PM_CHUNKS) return;
    size_t gid = chunk*8;
    int p   = (int)(gid / PLANE);
    int rem = (int)(gid % PLANE);
    int i = rem / NP_, p0 = rem % NP_;
    frag8 o;
    if (p < H_){
      #pragma unroll
      for (int m = 0; m < 8; m++){
        int j = pm_srcj(p0 + m); float v = 0.f;
        if (i < N_ && j < N_){
          int r = rel[i*N_ + j];
          v = ldf(table, (size_t)r*H_ + p, F32) * LOG2E;
        }
        o.s[m] = (short)f2bf(v);
      }
    } else {
      int w = p - H_;
      #pragma unroll
      for (int m = 0; m < 8; m++){
        int j = pm_srcj(p0 + m); float v = 0.f;
        if (i < N_ && j < N_)
          v = ldf(mask, (size_t)w*NN_ + (size_t)i*N_ + j, F32) * LOG2E;
        o.s[m] = (short)f2bf(v);
      }
    }
    *(uint4*)&pm[gid] = o.u4;
    return;
  }

  // ---- kv path (b = bx) ----
  const int b = bx;
  const int lane = t & 63, wave = t >> 6;
  const int n16 = lane & 15, q = lane >> 4;

  float kvb[3];
  u16*  p3[3];
  int   d3[3], isK[3];
  frag8 bw[3][6];
  #pragma unroll
  for (int c3 = 0; c3 < 3; c3++){
    int col = (wave*3 + c3)*16 + n16;        // 0..383
    kvb[c3] = ldf(kv_b, col, F32);
    #pragma unroll
    for (int ks = 0; ks < 6; ks++)
      #pragma unroll
      for (int j = 0; j < 8; j++)
        bw[c3][ks].s[j] = (short)f2bf(ldf(kv_w, (size_t)(ks*32 + q*8 + j)*384 + col, F32));
    if (col < 192){
      int h = col >> 5; d3[c3] = col & 31; isK[c3] = 1;
      p3[c3] = kvws + (size_t)(b*H_ + h)*22528;
    } else {
      int cv = col - 192; int h = cv >> 5; d3[c3] = cv & 31; isK[c3] = 0;
      p3[c3] = kvws + (size_t)(b*H_ + h)*22528 + 11264;
    }
  }

  const int r0 = t/24,        c0 = (t%24)*8;
  const int r1 = (t+512)/24,  c1 = ((t+512)%24)*8;
  const bool two = (t < 256);
  uint4 pre0 = ld_row8(skip, F32, b, r0, c0);
  uint4 pre1 = two ? ld_row8(skip, F32, b, r1, c1) : make_uint4(0,0,0,0);

  for (int rc = 0; rc < 11; rc++){
    __syncthreads();
    *(uint4*)&sk[r0*200 + c0] = pre0;
    if (two) *(uint4*)&sk[r1*200 + c1] = pre1;
    __syncthreads();
    if (rc < 10){
      int rb = (rc+1)*32;
      pre0 = ld_row8(skip, F32, b, rb + r0, c0);
      if (two) pre1 = ld_row8(skip, F32, b, rb + r1, c1);
    }
    frag8 af[2][6];
    #pragma unroll
    for (int half = 0; half < 2; half++)
      #pragma unroll
      for (int ks = 0; ks < 6; ks++)
        af[half][ks].u4 = *(const uint4*)&sk[(half*16 + n16)*200 + ks*32 + q*8];
    #pragma unroll
    for (int c3 = 0; c3 < 3; c3++){
      #pragma unroll
      for (int half = 0; half < 2; half++){
        f32x4 acc = {0.f,0.f,0.f,0.f};
        #pragma unroll
        for (int ks = 0; ks < 6; ks++)
          acc = __builtin_amdgcn_mfma_f32_16x16x32_bf16(af[half][ks].h8, bw[c3][ks].h8, acc, 0,0,0);
        #pragma unroll
        for (int r = 0; r < 4; r++){
          int grow = rc*32 + half*16 + q*4 + r;   // up to 351 (finite pad rows kept)
          u16 val = f2bf(acc[r] + kvb[c3]);
          if (isK[c3]) p3[c3][grow*32 + d3[c3]] = val;     // K linear [j][d]
          else         p3[c3][d3[c3]*352 + grow] = val;    // V^T linear [d][j]
        }
      }
    }
  }
}

// attn2: ZERO LDS — K/V^T fragments read directly from kvws (L2-resident panels:
// 4 resident blocks/CU x 45 KB << 4 MB/XCD). No copy phase, no barriers,
// occupancy at the 32-wave cap. Swapped-QK^T in-register softmax as before.
__global__ __launch_bounds__(512, 8) void attn2(
    const void* __restrict__ skip, const void* __restrict__ x_up,
    const u16* __restrict__ bp, const u16* __restrict__ msp,
    const u16* __restrict__ kvws,
    u16* __restrict__ xws, void* __restrict__ out){
  const bool F32 = detect_f32((const uint32*)skip);
  const int bid = blockIdx.x;
  const int b = bid / H_, h = bid % H_;
  const int w = b & (NW_-1);
  const int t = threadIdx.x, lane = t & 63, wave = t >> 6;
  const int n16 = lane & 15, q = lane >> 4;

  const u16* kK = kvws + (size_t)bid*22528;        // K linear [352][32]
  const u16* kV = kK + 11264;                      // V^T linear [32][352]
  const u16* bpl = bp  + (size_t)h*PLANE;
  const u16* mpl = msp + (size_t)w*PLANE;
  const float SC2 = 0.17677669529663687f * 1.4426950408889634f;  // scale * log2e
  const int src0 = ((q & 1) << 5) + n16;   // shfl sources (loop-invariant)
  const int src1 = src0 + 16;
  const bool lo = (q < 2);

  for (int it = wave; it < 22; it += 8){
    int i0 = it*16;
    const u16* br = bpl + (size_t)(i0 + n16)*NP_ + q*8;   // lane-local packed row
    const u16* mr = mpl + (size_t)(i0 + n16)*NP_ + q*8;
    frag8 aq;   // Q[i=i0+n16][d=q*8..+7] (B-operand of swapped QK^T)
    {
      int qrow = min(i0 + n16, N_-1);
      size_t base = ((size_t)b*N_ + qrow)*C_ + h*D_ + q*8;
      if (F32){
        const float* xf = (const float*)x_up + base;
        float4 f0 = *(const float4*)xf, f1 = *(const float4*)(xf + 4);
        aq.s[0]=(short)f2bf(f0.x); aq.s[1]=(short)f2bf(f0.y);
        aq.s[2]=(short)f2bf(f0.z); aq.s[3]=(short)f2bf(f0.w);
        aq.s[4]=(short)f2bf(f1.x); aq.s[5]=(short)f2bf(f1.y);
        aq.s[6]=(short)f2bf(f1.z); aq.s[7]=(short)f2bf(f1.w);
      } else {
        aq.u4 = *(const uint4*)((const u16*)x_up + base);
      }
    }
    f32x4 O0 = {0.f,0.f,0.f,0.f}, O1 = {0.f,0.f,0.f,0.f};
    float lp = 0.f;                                   // row-i denominator (partial)
    for (int jc = 0; jc < 11; jc++){
      int j0 = jc*32;
      // packed: e[0..3] = half0 (ja), e[4..7] = half1 (jb)
      union U8 { uint4 v; u16 e[8]; } Bv, Mv;
      Bv.v = *(const uint4*)&br[j0];
      Mv.v = *(const uint4*)&mr[j0];
      frag8 bk0, bk1;                                 // K rows as A-operand (global)
      bk0.u4 = *(const uint4*)&kK[(j0 + n16)*32 + q*8];
      bk1.u4 = *(const uint4*)&kK[(j0 + 16 + n16)*32 + q*8];
      f32x4 z = {0.f,0.f,0.f,0.f};
      // swapped: D[m=j_local][n=i_local] -> lane holds S[i=i0+n16][j=j0+q*4+r]
      f32x4 s0 = __builtin_amdgcn_mfma_f32_16x16x32_bf16(bk0.h8, aq.h8, z, 0,0,0);
      f32x4 s1 = __builtin_amdgcn_mfma_f32_16x16x32_bf16(bk1.h8, aq.h8, z, 0,0,0);
      float pa[4], pb[4];
      if (jc < 10){                                   // no masking needed (j <= 335)
        #pragma unroll
        for (int r = 0; r < 4; r++){
          pa[r] = exp2f(fmaf(s0[r], SC2, bf2f(Bv.e[r])   + bf2f(Mv.e[r])));
          pb[r] = exp2f(fmaf(s1[r], SC2, bf2f(Bv.e[4+r]) + bf2f(Mv.e[4+r])));
          lp += pa[r] + pb[r];
        }
      } else {                                        // jc=10: mask j>=343 in pb
        #pragma unroll
        for (int r = 0; r < 4; r++){
          pa[r] = exp2f(fmaf(s0[r], SC2, bf2f(Bv.e[r]) + bf2f(Mv.e[r])));
          float eb = exp2f(fmaf(s1[r], SC2, bf2f(Bv.e[4+r]) + bf2f(Mv.e[4+r])));
          pb[r] = (336 + q*4 + r < N_) ? eb : 0.f;
          lp += pa[r] + pb[r];
        }
      }
      // P -> bf16 pairs (lane-local row), then redistribute to PV A-frag layout
      uint32 A0, A1, B0, B1;
      asm("v_cvt_pk_bf16_f32 %0, %1, %2" : "=v"(A0) : "v"(pa[0]), "v"(pa[1]));
      asm("v_cvt_pk_bf16_f32 %0, %1, %2" : "=v"(A1) : "v"(pa[2]), "v"(pa[3]));
      asm("v_cvt_pk_bf16_f32 %0, %1, %2" : "=v"(B0) : "v"(pb[0]), "v"(pb[1]));
      asm("v_cvt_pk_bf16_f32 %0, %1, %2" : "=v"(B1) : "v"(pb[2]), "v"(pb[3]));
      // target (q,n16) needs P[i=n16][j=q*8..+7]: sources lanes (q&1)*32+n16, +16
      uint32 a0s = (uint32)__shfl((int)A0, src0), a1s = (uint32)__shfl((int)A1, src0);
      uint32 a2s = (uint32)__shfl((int)A0, src1), a3s = (uint32)__shfl((int)A1, src1);
      uint32 b0s = (uint32)__shfl((int)B0, src0), b1s = (uint32)__shfl((int)B1, src0);
      uint32 b2s = (uint32)__shfl((int)B0, src1), b3s = (uint32)__shfl((int)B1, src1);
      frag8 ap;
      ap.u4.x = lo ? a0s : b0s;
      ap.u4.y = lo ? a1s : b1s;
      ap.u4.z = lo ? a2s : b2s;
      ap.u4.w = lo ? a3s : b3s;
      frag8 bv0, bv1;                                 // V^T rows (global)
      bv0.u4 = *(const uint4*)&kV[n16*352 + j0 + q*8];
      bv1.u4 = *(const uint4*)&kV[(16 + n16)*352 + j0 + q*8];
      O0 = __builtin_amdgcn_mfma_f32_16x16x32_bf16(ap.h8, bv0.h8, O0, 0,0,0);
      O1 = __builtin_amdgcn_mfma_f32_16x16x32_bf16(ap.h8, bv1.h8, O1, 0,0,0);
    }
    // full denominator for row i0+n16 (q-groups hold disjoint j's)
    lp += __shfl_xor(lp, 16);
    lp += __shfl_xor(lp, 32);
    #pragma unroll
    for (int r = 0; r < 4; r++){
      int il = q*4 + r;
      float rl = 1.f / __shfl(lp, (lane & 48) | il);   // lsum lives at n16 == il
      int i = i0 + il;
      if (i < N_){
        if (xws){
          u16* xp = xws + ((size_t)(b*H_ + h)*N_ + i)*D_;
          xp[n16]      = f2bf(O0[r]*rl);
          xp[16 + n16] = f2bf(O1[r]*rl);
        } else {
          size_t ob = ((size_t)b*N_ + i)*C_ + h*D_;
          stf(out, ob + n16,      O0[r]*rl, F32);
          stf(out, ob + 16 + n16, O1[r]*rl, F32);
        }
      }
    }
  }
}

// proj4: read bf16 xws, write d_out ONCE via LDS-staged full-line vector stores.
__global__ __launch_bounds__(256, 4) void proj4(const u16* __restrict__ xws,
                                                void* __restrict__ outp,
                                                const void* __restrict__ pw,
                                                const void* __restrict__ pb,
                                                const void* __restrict__ skip){
  __shared__ __align__(16) u16 xs[64*200];     // 25600 B
  __shared__ __align__(16) float os[16*196];   // 12544 B (pad 196 breaks q-bank aliasing)
  const bool F32 = detect_f32((const uint32*)skip);
  const int t = threadIdx.x, lane = t & 63, wave = t >> 6;
  const int n16 = lane & 15, q = lane >> 4;
  const size_t row0 = (size_t)blockIdx.x * 64;

  for (int u = t; u < 1536; u += 256){
    int r = u / 24, c8 = u % 24;
    int g = (int)row0 + r;
    int b = g / N_, i = g - b*N_;
    int h = c8 >> 2, d0 = (c8 & 3)*8;
    uint4 vv = *(const uint4*)&xws[((size_t)(b*H_ + h)*N_ + i)*D_ + d0];
    *(uint4*)&xs[r*200 + h*32 + d0] = vv;
  }
  frag8 bwf[3][6];
  float pbv[3];
  #pragma unroll
  for (int c3 = 0; c3 < 3; c3++){
    int col = (wave*3 + c3)*16 + n16;
    pbv[c3] = ldf(pb, col, F32);
    #pragma unroll
    for (int ks = 0; ks < 6; ks++)
      #pragma unroll
      for (int j = 0; j < 8; j++)
        bwf[c3][ks].s[j] = (short)f2bf(ldf(pw, (size_t)(ks*32 + q*8 + j)*C_ + col, F32));
  }
  __syncthreads();
  for (int rt = 0; rt < 4; rt++){
    frag8 af[6];
    #pragma unroll
    for (int ks = 0; ks < 6; ks++)
      af[ks].u4 = *(const uint4*)&xs[(rt*16 + n16)*200 + ks*32 + q*8];
    #pragma unroll
    for (int c3 = 0; c3 < 3; c3++){
      f32x4 acc = {0.f,0.f,0.f,0.f};
      #pragma unroll
      for (int ks = 0; ks < 6; ks++)
        acc = __builtin_amdgcn_mfma_f32_16x16x32_bf16(af[ks].h8, bwf[c3][ks].h8, acc, 0,0,0);
      int col = (wave*3 + c3)*16 + n16;
      #pragma unroll
      for (int r = 0; r < 4; r++)
        os[(q*4 + r)*196 + col] = acc[r] + pbv[c3];
    }
    __syncthreads();
    size_t rb = row0 + rt*16;
    if (F32){
      for (int u = t; u < 768; u += 256){     // 768 float4: 48 per row
        int r = u / 48, c4 = (u % 48)*4;
        *(float4*)((float*)outp + (rb + r)*C_ + c4) = *(const float4*)&os[r*196 + c4];
      }
    } else {
      for (int u = t; u < 384; u += 256){     // 384 u16x8: 24 per row
        int r = u / 24, c8 = (u % 24)*8;
        frag8 o;
        #pragma unroll
        for (int m = 0; m < 8; m++) o.s[m] = (short)f2bf(os[r*196 + c8 + m]);
        *(uint4*)((u16*)outp + (rb + r)*C_ + c8) = o.u4;
      }
    }
    __syncthreads();
  }
}

/* ====================== fallback-path kernels ====================== */

__global__ void prep_biasg(const void* __restrict__ skip, const int* __restrict__ rel,
                           const void* __restrict__ table, u16* __restrict__ biasg){
  const bool F32 = detect_f32((const uint32*)skip);
  int idx = blockIdx.x*256 + threadIdx.x;
  if (idx >= NN_) return;
  int r = rel[idx];
  #pragma unroll
  for (int h = 0; h < H_; h++)
    biasg[(size_t)h*NN_ + idx] = f2bf(ldf(table, (size_t)r*H_ + h, F32));
}

#define KLS_OFF 6400
#define VT_OFF  (KLS_OFF + 352*40)
#define SMEM_U16 (VT_OFF + 32*360)

__global__ __launch_bounds__(512, 4) void attn_fused(
    const void* __restrict__ skip, const void* __restrict__ x_up,
    const void* __restrict__ mask, const u16* __restrict__ biasg,
    const void* __restrict__ kv_w, const void* __restrict__ kv_b,
    void* __restrict__ out){
  __shared__ __align__(16) u16 sm[SMEM_U16];
  const bool F32 = detect_f32((const uint32*)skip);
  const int bid = blockIdx.x;
  const int b = bid / H_, h = bid % H_;
  const int w = b & (NW_-1);
  const int t = threadIdx.x;
  const int lane = t & 63, wave = t >> 6;
  const int n16 = lane & 15, q = lane >> 4;
  const int colt = wave & 3;
  const int half = wave >> 2;
  const int gcol = (colt < 2) ? (h*D_ + colt*16 + n16)
                              : (C_ + h*D_ + (colt-2)*16 + n16);
  const float kvb = ldf(kv_b, gcol, F32);
  frag8 bw[6];
  #pragma unroll
  for (int ks = 0; ks < 6; ks++)
    #pragma unroll
    for (int j = 0; j < 8; j++)
      bw[ks].s[j] = (short)f2bf(ldf(kv_w, (size_t)(ks*32 + q*8 + j)*384 + gcol, F32));

  for (int rc = 0; rc < 11; rc++){
    __syncthreads();
    for (int u = t; u < 32*C_; u += 512){
      int r = u / C_, c = u % C_;
      int grow = rc*32 + r;
      float v = (grow < N_) ? ldf(skip, ((size_t)b*N_ + grow)*C_ + c, F32) : 0.f;
      sm[r*200 + c] = f2bf(v);
    }
    __syncthreads();
    f32x4 acc = {0.f, 0.f, 0.f, 0.f};
    #pragma unroll
    for (int ks = 0; ks < 6; ks++){
      frag8 a;  a.u4 = *(const uint4*)&sm[(half*16 + n16)*200 + ks*32 + q*8];
      acc = __builtin_amdgcn_mfma_f32_16x16x32_bf16(a.h8, bw[ks].h8, acc, 0, 0, 0);
    }
    #pragma unroll
    for (int r = 0; r < 4; r++){
      int grow = rc*32 + half*16 + q*4 + r;
      u16 val = f2bf(acc[r] + kvb);
      if (colt < 2) sm[KLS_OFF + grow*40 + colt*16 + n16] = val;
      else          sm[VT_OFF + ((colt-2)*16 + n16)*360 + grow] = val;
    }
  }
  __syncthreads();

  const float scale = 0.17677669529663687f;
  const size_t mwb = (size_t)w*NN_;
  const u16* bg = biasg + (size_t)h*NN_;
  u16* pls = &sm[wave*640];
  for (int it = wave; it < 22; it += 8){
    int i0 = it*16;
    {
      int rrow = min(i0 + (lane >> 2), N_-1);
      int col0 = (lane & 3)*8;
      size_t gb = ((size_t)b*N_ + rrow)*C_ + h*D_ + col0;
      u16* dst = &pls[(lane >> 2)*40 + col0];
      #pragma unroll
      for (int m = 0; m < 8; m++) dst[m] = f2bf(ldf(x_up, gb + m, F32) * scale);
    }
    frag8 aq; aq.u4 = *(const uint4*)&pls[n16*40 + q*8];
    f32x4 O0 = {0.f,0.f,0.f,0.f}, O1 = {0.f,0.f,0.f,0.f};
    float lp[4] = {0.f, 0.f, 0.f, 0.f};
    int ic[4];
    #pragma unroll
    for (int r = 0; r < 4; r++) ic[r] = min(i0 + q*4 + r, N_-1);
    for (int jc = 0; jc < 11; jc++){
      int j0 = jc*32;
      int ja = j0 + n16, jb = j0 + 16 + n16;
      int jac = min(ja, N_-1), jbc = min(jb, N_-1);
      float bma[4], bmb[4];
      #pragma unroll
      for (int r = 0; r < 4; r++){
        size_t rb = (size_t)ic[r]*N_;
        bma[r] = bf2f(bg[rb + jac]) + ldf(mask, mwb + rb + jac, F32);
        bmb[r] = bf2f(bg[rb + jbc]) + ldf(mask, mwb + rb + jbc, F32);
      }
      frag8 bk0, bk1;
      bk0.u4 = *(const uint4*)&sm[KLS_OFF + (j0 + n16)*40 + q*8];
      bk1.u4 = *(const uint4*)&sm[KLS_OFF + (j0 + 16 + n16)*40 + q*8];
      f32x4 z = {0.f,0.f,0.f,0.f};
      f32x4 s0 = __builtin_amdgcn_mfma_f32_16x16x32_bf16(aq.h8, bk0.h8, z, 0,0,0);
      f32x4 s1 = __builtin_amdgcn_mfma_f32_16x16x32_bf16(aq.h8, bk1.h8, z, 0,0,0);
      #pragma unroll
      for (int r = 0; r < 4; r++){
        float pa = (ja < N_) ? __expf(s0[r] + bma[r] - 12.f) : 0.f;
        float pb = (jb < N_) ? __expf(s1[r] + bmb[r] - 12.f) : 0.f;
        lp[r] += pa + pb;
        pls[(q*4 + r)*40 + n16]      = f2bf(pa);
        pls[(q*4 + r)*40 + 16 + n16] = f2bf(pb);
      }
      frag8 ap; ap.u4 = *(const uint4*)&pls[n16*40 + q*8];
      frag8 bv0, bv1;
      bv0.u4 = *(const uint4*)&sm[VT_OFF + n16*360 + j0 + q*8];
      bv1.u4 = *(const uint4*)&sm[VT_OFF + (16 + n16)*360 + j0 + q*8];
      O0 = __builtin_amdgcn_mfma_f32_16x16x32_bf16(ap.h8, bv0.h8, O0, 0,0,0);
      O1 = __builtin_amdgcn_mfma_f32_16x16x32_bf16(ap.h8, bv1.h8, O1, 0,0,0);
    }
    #pragma unroll
    for (int msk = 1; msk < 16; msk <<= 1){
      #pragma unroll
      for (int r = 0; r < 4; r++) lp[r] += __shfl_xor(lp[r], msk, 64);
    }
    #pragma unroll
    for (int r = 0; r < 4; r++){
      int i = i0 + q*4 + r;
      if (i < N_){
        float rl = 1.f / lp[r];
        size_t ob = ((size_t)b*N_ + i)*C_ + h*D_;
        stf(out, ob + n16,      O0[r]*rl, F32);
        stf(out, ob + 16 + n16, O1[r]*rl, F32);
      }
    }
  }
}

/* ---- in-place projection (tier-B fallback) ---- */
__global__ __launch_bounds__(256, 6) void proj2(void* __restrict__ io,
                                                const void* __restrict__ pw,
                                                const void* __restrict__ pb,
                                                const void* __restrict__ skip){
  __shared__ __align__(16) u16 xs[64*200];   // 25600 B
  const bool F32 = detect_f32((const uint32*)skip);
  const int t = threadIdx.x;
  const int lane = t & 63, wave = t >> 6;
  const int n16 = lane & 15, q = lane >> 4;
  const size_t row0 = (size_t)blockIdx.x * 64;

  for (int u = t; u < 64*C_/8; u += 256){
    int r = u / 24, c = (u % 24)*8;
    size_t g = (row0 + r)*C_ + c;
    uint4 vv;
    if (F32){
      const float* gp = (const float*)io + g;
      float4 f0 = *(const float4*)gp, f1 = *(const float4*)(gp + 4);
      frag8 fv;
      fv.s[0]=(short)f2bf(f0.x); fv.s[1]=(short)f2bf(f0.y);
      fv.s[2]=(short)f2bf(f0.z); fv.s[3]=(short)f2bf(f0.w);
      fv.s[4]=(short)f2bf(f1.x); fv.s[5]=(short)f2bf(f1.y);
      fv.s[6]=(short)f2bf(f1.z); fv.s[7]=(short)f2bf(f1.w);
      vv = fv.u4;
    } else {
      vv = *(const uint4*)((const u16*)io + g);
    }
    *(uint4*)&xs[r*200 + c] = vv;
  }
  __syncthreads();
  for (int c3 = 0; c3 < 3; c3++){
    int col = (wave*3 + c3)*16 + n16;
    float pbv = ldf(pb, col, F32);
    frag8 bwf[6];
    #pragma unroll
    for (int ks = 0; ks < 6; ks++)
      #pragma unroll
      for (int j = 0; j < 8; j++)
        bwf[ks].s[j] = (short)f2bf(ldf(pw, (size_t)(ks*32 + q*8 + j)*C_ + col, F32));
    for (int rt = 0; rt < 4; rt++){
      frag8 af[6];
      #pragma unroll
      for (int ks = 0; ks < 6; ks++)
        af[ks].u4 = *(const uint4*)&xs[(rt*16 + n16)*200 + ks*32 + q*8];
      f32x4 acc = {0.f,0.f,0.f,0.f};
      #pragma unroll
      for (int ks = 0; ks < 6; ks++)
        acc = __builtin_amdgcn_mfma_f32_16x16x32_bf16(af[ks].h8, bwf[ks].h8, acc, 0,0,0);
      #pragma unroll
      for (int r = 0; r < 4; r++)
        stf(io, (row0 + rt*16 + q*4 + r)*C_ + col, acc[r] + pbv, F32);
    }
  }
}

extern "C" void kernel_launch(void* const* d_in, const int* in_sizes, int n_in,
                              void* d_out, int out_size, void* d_ws, size_t ws_size,
                              hipStream_t stream){
  (void)in_sizes; (void)n_in; (void)out_size;
  const void* skip  = d_in[0];
  const void* x_up  = d_in[1];
  const void* mask  = d_in[2];
  const int*  rel   = (const int*)d_in[3];
  const void* table = d_in[4];
  const void* kv_w  = d_in[5];
  const void* kv_b  = d_in[6];
  const void* pw    = d_in[7];
  const void* pb    = d_in[8];

  const size_t PM_BYTES = (size_t)PM_PLANES*PLANE*2;  //  9,416,704
  const size_t KV_BYTES = (size_t)B_*H_*45056;        // 69,206,016
  const size_t XW_BYTES = (size_t)B_*H_*N_*D_*2;      // 33,718,272

  if (ws_size >= PM_BYTES + KV_BYTES + XW_BYTES){
    // Tier A: fused kv+pm (linear K/V^T, packed planes) -> attn2 (no LDS) -> proj4
    u16* pm   = (u16*)d_ws;
    u16* bpp  = pm;                       // planes 0..5
    u16* msp  = pm + (size_t)H_*PLANE;    // planes 6..37
    u16* kvws = (u16*)((char*)d_ws + PM_BYTES);
    u16* xws  = (u16*)((char*)d_ws + PM_BYTES + KV_BYTES);
    kv_pm<<<B_ + PM_BLKS, 512, 0, stream>>>(skip, kv_w, kv_b, kvws, rel, table, mask, pm);
    attn2<<<B_*H_, 512, 0, stream>>>(skip, x_up, bpp, msp, kvws, xws, d_out);
    proj4<<<87808/64, 256, 0, stream>>>(xws, d_out, pw, pb, skip);
  } else if (ws_size >= PM_BYTES + KV_BYTES){
    // Tier B: no xws -> attn2 writes out, in-place proj
    u16* pm   = (u16*)d_ws;
    u16* bpp  = pm;
    u16* msp  = pm + (size_t)H_*PLANE;
    u16* kvws = (u16*)((char*)d_ws + PM_BYTES);
    kv_pm<<<B_ + PM_BLKS, 512, 0, stream>>>(skip, kv_w, kv_b, kvws, rel, table, mask, pm);
    attn2<<<B_*H_, 512, 0, stream>>>(skip, x_up, bpp, msp, kvws, nullptr, d_out);
    proj2<<<87808/64, 256, 0, stream>>>(d_out, pw, pb, skip);
  } else {
    u16* biasg = (u16*)d_ws;   // 1.41 MB
    prep_biasg<<<(NN_+255)/256, 256, 0, stream>>>(skip, rel, table, biasg);
    attn_fused<<<B_*H_, 512, 0, stream>>>(skip, x_up, mask, biasg, kv_w, kv_b, d_out);
    proj2     <<<87808/64, 256, 0, stream>>>(d_out, pw, pb, skip);
  }
}

// Round 16
// 398.036 us; speedup vs baseline: 1.2037x; 1.2037x over previous
//
#include <hip/hip_runtime.h>
#include <hip/hip_bf16.h>

#define B_  256
#define N_  343
#define C_  192
#define H_  6
#define D_  32
#define NW_ 32
#define NN_ (N_*N_)     /* 117649 */
#define TROWS 2197
#define NP_ 352                    /* padded N */
#define PLANE (NP_*NP_)            /* 123904 u16 per plane */

typedef unsigned int  uint32;
typedef unsigned short u16;
typedef __attribute__((ext_vector_type(8))) short bf16x8;
typedef __attribute__((ext_vector_type(4))) float f32x4;

union frag8 { uint4 u4; bf16x8 h8; short s[8]; };

__device__ __forceinline__ float bf2f(u16 u){
  union { uint32 u; float f; } v; v.u = ((uint32)u) << 16; return v.f;
}
__device__ __forceinline__ u16 f2bf(float f){
  union { float f; uint32 u; } v; v.f = f;
  uint32 u = v.u;
  return (u16)((u + 0x7FFFu + ((u >> 16) & 1u)) >> 16);  // RNE
}

// Deterministic dtype sniff (fp32 vs bf16 input world).
__device__ __forceinline__ bool detect_f32(const uint32* w){
  int c = 0;
  #pragma unroll
  for (int u = 0; u < 32; u++){
    int e = (w[u*37] >> 7) & 0xFF;
    c += (e > 150);
  }
  return c >= 3;
}
__device__ __forceinline__ float ldf(const void* p, size_t i, bool f32){
  return f32 ? ((const float*)p)[i] : bf2f(((const u16*)p)[i]);
}
__device__ __forceinline__ void stf(void* p, size_t i, float v, bool f32){
  if (f32) ((float*)p)[i] = v;
  else     ((u16*)p)[i]   = f2bf(v);
}

// ---- swizzled index helpers (shared by writer + reader => consistency) ----
__device__ __forceinline__ int klsidx(int j, int d){
  return j*32 + ((((d>>3) ^ ((j>>2)&3)))<<3) + (d&7);
}
__device__ __forceinline__ int vtidx(int d, int j){
  return d*352 + ((((j>>3) ^ ((d>>2)&3)))<<3) + (j&7);
}

// packed-plane column decode: packed p = jc*32 + q*8 + half*4 + r  ->  source j
__device__ __forceinline__ int pm_srcj(int p){
  int jc = p >> 5, wi = p & 31;
  return (jc << 5) + ((wi >> 2) & 1)*16 + (wi >> 3)*4 + (wi & 3);
}

// 8 bf16 row-chunk load (zero-pad beyond N_ rows)
__device__ __forceinline__ uint4 ld_row8(const void* __restrict__ src, bool F32,
                                         int b, int grow, int col){
  if (grow >= N_) return make_uint4(0,0,0,0);
  size_t g = ((size_t)b*N_ + grow)*C_ + col;
  if (F32){
    const float* gp = (const float*)src + g;
    float4 f0 = *(const float4*)gp, f1 = *(const float4*)(gp + 4);
    frag8 fv;
    fv.s[0]=(short)f2bf(f0.x); fv.s[1]=(short)f2bf(f0.y);
    fv.s[2]=(short)f2bf(f0.z); fv.s[3]=(short)f2bf(f0.w);
    fv.s[4]=(short)f2bf(f1.x); fv.s[5]=(short)f2bf(f1.y);
    fv.s[6]=(short)f2bf(f1.z); fv.s[7]=(short)f2bf(f1.w);
    return fv.u4;
  }
  return *(const uint4*)((const u16*)src + g);
}

/* ====================== big-ws path kernels ====================== */

#define PM_PLANES (H_ + NW_)   /* 38: bp 6 planes + msp 32 planes */
#define PM_CHUNKS ((size_t)PM_PLANES*PLANE/8)   /* 588544 */
#define PM_BLKS   ((int)((PM_CHUNKS + 511)/512))  /* 1150 */

// Fat kernel: blocks [0,256) = KV GEMM (now double-buffered LDS, 1 barrier per
// chunk — R9's likely-positive change retried on the R14 base); blocks
// [256,...) = packed split-plane prep (proven non-interfering R13/R14).
__global__ __launch_bounds__(512, 2) void kv_pm(
    const void* __restrict__ skip, const void* __restrict__ kv_w,
    const void* __restrict__ kv_b, u16* __restrict__ kvws,
    const int* __restrict__ rel, const void* __restrict__ table,
    const void* __restrict__ mask, u16* __restrict__ pm){
  __shared__ __align__(16) u16 sk[2][32*200];   // 25.6 KB (kv path only)
  const bool F32 = detect_f32((const uint32*)skip);
  const int bx = blockIdx.x;
  const int t = threadIdx.x;

  if (bx >= B_){
    // ---- pm path (packed columns) ----
    const float LOG2E = 1.4426950408889634f;
    size_t chunk = (size_t)(bx - B_)*512 + t;
    if (chunk >= PM_CHUNKS) return;
    size_t gid = chunk*8;
    int p   = (int)(gid / PLANE);
    int rem = (int)(gid % PLANE);
    int i = rem / NP_, p0 = rem % NP_;
    frag8 o;
    if (p < H_){
      #pragma unroll
      for (int m = 0; m < 8; m++){
        int j = pm_srcj(p0 + m); float v = 0.f;
        if (i < N_ && j < N_){
          int r = rel[i*N_ + j];
          v = ldf(table, (size_t)r*H_ + p, F32) * LOG2E;
        }
        o.s[m] = (short)f2bf(v);
      }
    } else {
      int w = p - H_;
      #pragma unroll
      for (int m = 0; m < 8; m++){
        int j = pm_srcj(p0 + m); float v = 0.f;
        if (i < N_ && j < N_)
          v = ldf(mask, (size_t)w*NN_ + (size_t)i*N_ + j, F32) * LOG2E;
        o.s[m] = (short)f2bf(v);
      }
    }
    *(uint4*)&pm[gid] = o.u4;
    return;
  }

  // ---- kv path (b = bx), double-buffered LDS ----
  const int b = bx;
  const int lane = t & 63, wave = t >> 6;
  const int n16 = lane & 15, q = lane >> 4;

  float kvb[3];
  u16*  p3[3];
  int   d3[3], isK[3];
  frag8 bw[3][6];
  #pragma unroll
  for (int c3 = 0; c3 < 3; c3++){
    int col = (wave*3 + c3)*16 + n16;        // 0..383
    kvb[c3] = ldf(kv_b, col, F32);
    #pragma unroll
    for (int ks = 0; ks < 6; ks++)
      #pragma unroll
      for (int j = 0; j < 8; j++)
        bw[c3][ks].s[j] = (short)f2bf(ldf(kv_w, (size_t)(ks*32 + q*8 + j)*384 + col, F32));
    if (col < 192){
      int h = col >> 5; d3[c3] = col & 31; isK[c3] = 1;
      p3[c3] = kvws + (size_t)(b*H_ + h)*22528;
    } else {
      int cv = col - 192; int h = cv >> 5; d3[c3] = cv & 31; isK[c3] = 0;
      p3[c3] = kvws + (size_t)(b*H_ + h)*22528 + 11264;
    }
  }

  // staging map: 768 8-elem chunks; thread t owns chunk t (all) and 512+t (t<256)
  const int r0 = t/24,        c0 = (t%24)*8;
  const int r1 = (t+512)/24,  c1 = ((t+512)%24)*8;
  const bool two = (t < 256);

  // prologue: chunk 0 -> sk[0]; chunk 1 -> regs (cur)
  {
    uint4 a0 = ld_row8(skip, F32, b, r0, c0);
    uint4 a1 = two ? ld_row8(skip, F32, b, r1, c1) : make_uint4(0,0,0,0);
    *(uint4*)&sk[0][r0*200 + c0] = a0;
    if (two) *(uint4*)&sk[0][r1*200 + c1] = a1;
  }
  uint4 cur0 = ld_row8(skip, F32, b, 32 + r0, c0);
  uint4 cur1 = two ? ld_row8(skip, F32, b, 32 + r1, c1) : make_uint4(0,0,0,0);
  __syncthreads();

  for (int rc = 0; rc < 11; rc++){
    const u16* buf = sk[rc & 1];
    frag8 af[2][6];
    #pragma unroll
    for (int half = 0; half < 2; half++)
      #pragma unroll
      for (int ks = 0; ks < 6; ks++)
        af[half][ks].u4 = *(const uint4*)&buf[(half*16 + n16)*200 + ks*32 + q*8];
    if (rc < 10){
      // write chunk rc+1 into the other buffer (its readers finished at rc-1's barrier)
      u16* nbuf = sk[(rc + 1) & 1];
      *(uint4*)&nbuf[r0*200 + c0] = cur0;
      if (two) *(uint4*)&nbuf[r1*200 + c1] = cur1;
      if (rc < 9){
        int rb = (rc + 2)*32;
        cur0 = ld_row8(skip, F32, b, rb + r0, c0);
        if (two) cur1 = ld_row8(skip, F32, b, rb + r1, c1);
      }
    }
    #pragma unroll
    for (int c3 = 0; c3 < 3; c3++){
      #pragma unroll
      for (int half = 0; half < 2; half++){
        f32x4 acc = {0.f,0.f,0.f,0.f};
        #pragma unroll
        for (int ks = 0; ks < 6; ks++)
          acc = __builtin_amdgcn_mfma_f32_16x16x32_bf16(af[half][ks].h8, bw[c3][ks].h8, acc, 0,0,0);
        #pragma unroll
        for (int r = 0; r < 4; r++){
          int grow = rc*32 + half*16 + q*4 + r;   // up to 351 (finite pad rows kept)
          u16 val = f2bf(acc[r] + kvb[c3]);
          if (isK[c3]) p3[c3][klsidx(grow, d3[c3])] = val;
          else         p3[c3][vtidx(d3[c3], grow)] = val;
        }
      }
    }
    __syncthreads();   // reads of sk[rc&1] done; writes of sk[(rc+1)&1] visible
  }
}

// ---- attn2 LDS (u16 units): kls 11264 | vT 11264 = 22528 u16 = 45056 B
#define A2_VT  11264
#define A2_TOT 22528

// Swapped-QK^T in-register softmax; bias/mask from packed bp/msp planes:
// ONE uint4 per plane per jc covers both halves. (R14-proven 138 µs config.)
__global__ __launch_bounds__(512, 6) void attn2(
    const void* __restrict__ skip, const void* __restrict__ x_up,
    const u16* __restrict__ bp, const u16* __restrict__ msp,
    const u16* __restrict__ kvws,
    u16* __restrict__ xws, void* __restrict__ out){
  __shared__ __align__(16) u16 sm[A2_TOT];
  const bool F32 = detect_f32((const uint32*)skip);
  const int bid = blockIdx.x;
  const int b = bid / H_, h = bid % H_;
  const int w = b & (NW_-1);
  const int t = threadIdx.x, lane = t & 63, wave = t >> 6;
  const int n16 = lane & 15, q = lane >> 4;

  {
    const uint4* src = (const uint4*)(kvws + (size_t)bid*22528);
    uint4* dst = (uint4*)sm;
    for (int u = t; u < 2816; u += 512) dst[u] = src[u];
  }
  __syncthreads();

  const u16* bpl = bp  + (size_t)h*PLANE;
  const u16* mpl = msp + (size_t)w*PLANE;
  const float SC2 = 0.17677669529663687f * 1.4426950408889634f;  // scale * log2e
  const int src0 = ((q & 1) << 5) + n16;   // shfl sources (loop-invariant)
  const int src1 = src0 + 16;
  const bool lo = (q < 2);

  for (int it = wave; it < 22; it += 8){
    int i0 = it*16;
    const u16* br = bpl + (size_t)(i0 + n16)*NP_ + q*8;   // lane-local packed row
    const u16* mr = mpl + (size_t)(i0 + n16)*NP_ + q*8;
    frag8 aq;   // Q[i=i0+n16][d=q*8..+7] (B-operand of swapped QK^T)
    {
      int qrow = min(i0 + n16, N_-1);
      size_t base = ((size_t)b*N_ + qrow)*C_ + h*D_ + q*8;
      if (F32){
        const float* xf = (const float*)x_up + base;
        float4 f0 = *(const float4*)xf, f1 = *(const float4*)(xf + 4);
        aq.s[0]=(short)f2bf(f0.x); aq.s[1]=(short)f2bf(f0.y);
        aq.s[2]=(short)f2bf(f0.z); aq.s[3]=(short)f2bf(f0.w);
        aq.s[4]=(short)f2bf(f1.x); aq.s[5]=(short)f2bf(f1.y);
        aq.s[6]=(short)f2bf(f1.z); aq.s[7]=(short)f2bf(f1.w);
      } else {
        aq.u4 = *(const uint4*)((const u16*)x_up + base);
      }
    }
    f32x4 O0 = {0.f,0.f,0.f,0.f}, O1 = {0.f,0.f,0.f,0.f};
    float lp = 0.f;                                   // row-i denominator (partial)
    for (int jc = 0; jc < 11; jc++){
      int j0 = jc*32;
      // packed: e[0..3] = half0 (ja), e[4..7] = half1 (jb)
      union U8 { uint4 v; u16 e[8]; } Bv, Mv;
      Bv.v = *(const uint4*)&br[j0];
      Mv.v = *(const uint4*)&mr[j0];
      frag8 bk0, bk1;                                 // K rows as A-operand
      bk0.u4 = *(const uint4*)&sm[klsidx(j0 + n16, q*8)];
      bk1.u4 = *(const uint4*)&sm[klsidx(j0 + 16 + n16, q*8)];
      f32x4 z = {0.f,0.f,0.f,0.f};
      // swapped: D[m=j_local][n=i_local] -> lane holds S[i=i0+n16][j=j0+q*4+r]
      f32x4 s0 = __builtin_amdgcn_mfma_f32_16x16x32_bf16(bk0.h8, aq.h8, z, 0,0,0);
      f32x4 s1 = __builtin_amdgcn_mfma_f32_16x16x32_bf16(bk1.h8, aq.h8, z, 0,0,0);
      float pa[4], pb[4];
      if (jc < 10){                                   // no masking needed (j <= 335)
        #pragma unroll
        for (int r = 0; r < 4; r++){
          pa[r] = exp2f(fmaf(s0[r], SC2, bf2f(Bv.e[r])   + bf2f(Mv.e[r])));
          pb[r] = exp2f(fmaf(s1[r], SC2, bf2f(Bv.e[4+r]) + bf2f(Mv.e[4+r])));
          lp += pa[r] + pb[r];
        }
      } else {                                        // jc=10: mask j>=343 in pb
        #pragma unroll
        for (int r = 0; r < 4; r++){
          pa[r] = exp2f(fmaf(s0[r], SC2, bf2f(Bv.e[r]) + bf2f(Mv.e[r])));
          float eb = exp2f(fmaf(s1[r], SC2, bf2f(Bv.e[4+r]) + bf2f(Mv.e[4+r])));
          pb[r] = (336 + q*4 + r < N_) ? eb : 0.f;
          lp += pa[r] + pb[r];
        }
      }
      // P -> bf16 pairs (lane-local row), then redistribute to PV A-frag layout
      uint32 A0, A1, B0, B1;
      asm("v_cvt_pk_bf16_f32 %0, %1, %2" : "=v"(A0) : "v"(pa[0]), "v"(pa[1]));
      asm("v_cvt_pk_bf16_f32 %0, %1, %2" : "=v"(A1) : "v"(pa[2]), "v"(pa[3]));
      asm("v_cvt_pk_bf16_f32 %0, %1, %2" : "=v"(B0) : "v"(pb[0]), "v"(pb[1]));
      asm("v_cvt_pk_bf16_f32 %0, %1, %2" : "=v"(B1) : "v"(pb[2]), "v"(pb[3]));
      // target (q,n16) needs P[i=n16][j=q*8..+7]: sources lanes (q&1)*32+n16, +16
      uint32 a0s = (uint32)__shfl((int)A0, src0), a1s = (uint32)__shfl((int)A1, src0);
      uint32 a2s = (uint32)__shfl((int)A0, src1), a3s = (uint32)__shfl((int)A1, src1);
      uint32 b0s = (uint32)__shfl((int)B0, src0), b1s = (uint32)__shfl((int)B1, src0);
      uint32 b2s = (uint32)__shfl((int)B0, src1), b3s = (uint32)__shfl((int)B1, src1);
      frag8 ap;
      ap.u4.x = lo ? a0s : b0s;
      ap.u4.y = lo ? a1s : b1s;
      ap.u4.z = lo ? a2s : b2s;
      ap.u4.w = lo ? a3s : b3s;
      frag8 bv0, bv1;
      bv0.u4 = *(const uint4*)&sm[A2_VT + vtidx(n16,      j0 + q*8)];
      bv1.u4 = *(const uint4*)&sm[A2_VT + vtidx(16 + n16, j0 + q*8)];
      O0 = __builtin_amdgcn_mfma_f32_16x16x32_bf16(ap.h8, bv0.h8, O0, 0,0,0);
      O1 = __builtin_amdgcn_mfma_f32_16x16x32_bf16(ap.h8, bv1.h8, O1, 0,0,0);
    }
    // full denominator for row i0+n16 (q-groups hold disjoint j's)
    lp += __shfl_xor(lp, 16);
    lp += __shfl_xor(lp, 32);
    #pragma unroll
    for (int r = 0; r < 4; r++){
      int il = q*4 + r;
      float rl = 1.f / __shfl(lp, (lane & 48) | il);   // lsum lives at n16 == il
      int i = i0 + il;
      if (i < N_){
        if (xws){
          u16* xp = xws + ((size_t)(b*H_ + h)*N_ + i)*D_;
          xp[n16]      = f2bf(O0[r]*rl);
          xp[16 + n16] = f2bf(O1[r]*rl);
        } else {
          size_t ob = ((size_t)b*N_ + i)*C_ + h*D_;
          stf(out, ob + n16,      O0[r]*rl, F32);
          stf(out, ob + 16 + n16, O1[r]*rl, F32);
        }
      }
    }
  }
}

// proj4: read bf16 xws, write d_out ONCE via LDS-staged full-line vector stores.
__global__ __launch_bounds__(256, 4) void proj4(const u16* __restrict__ xws,
                                                void* __restrict__ outp,
                                                const void* __restrict__ pw,
                                                const void* __restrict__ pb,
                                                const void* __restrict__ skip){
  __shared__ __align__(16) u16 xs[64*200];     // 25600 B
  __shared__ __align__(16) float os[16*196];   // 12544 B (pad 196 breaks q-bank aliasing)
  const bool F32 = detect_f32((const uint32*)skip);
  const int t = threadIdx.x, lane = t & 63, wave = t >> 6;
  const int n16 = lane & 15, q = lane >> 4;
  const size_t row0 = (size_t)blockIdx.x * 64;

  for (int u = t; u < 1536; u += 256){
    int r = u / 24, c8 = u % 24;
    int g = (int)row0 + r;
    int b = g / N_, i = g - b*N_;
    int h = c8 >> 2, d0 = (c8 & 3)*8;
    uint4 vv = *(const uint4*)&xws[((size_t)(b*H_ + h)*N_ + i)*D_ + d0];
    *(uint4*)&xs[r*200 + h*32 + d0] = vv;
  }
  frag8 bwf[3][6];
  float pbv[3];
  #pragma unroll
  for (int c3 = 0; c3 < 3; c3++){
    int col = (wave*3 + c3)*16 + n16;
    pbv[c3] = ldf(pb, col, F32);
    #pragma unroll
    for (int ks = 0; ks < 6; ks++)
      #pragma unroll
      for (int j = 0; j < 8; j++)
        bwf[c3][ks].s[j] = (short)f2bf(ldf(pw, (size_t)(ks*32 + q*8 + j)*C_ + col, F32));
  }
  __syncthreads();
  for (int rt = 0; rt < 4; rt++){
    frag8 af[6];
    #pragma unroll
    for (int ks = 0; ks < 6; ks++)
      af[ks].u4 = *(const uint4*)&xs[(rt*16 + n16)*200 + ks*32 + q*8];
    #pragma unroll
    for (int c3 = 0; c3 < 3; c3++){
      f32x4 acc = {0.f,0.f,0.f,0.f};
      #pragma unroll
      for (int ks = 0; ks < 6; ks++)
        acc = __builtin_amdgcn_mfma_f32_16x16x32_bf16(af[ks].h8, bwf[c3][ks].h8, acc, 0,0,0);
      int col = (wave*3 + c3)*16 + n16;
      #pragma unroll
      for (int r = 0; r < 4; r++)
        os[(q*4 + r)*196 + col] = acc[r] + pbv[c3];
    }
    __syncthreads();
    size_t rb = row0 + rt*16;
    if (F32){
      for (int u = t; u < 768; u += 256){     // 768 float4: 48 per row
        int r = u / 48, c4 = (u % 48)*4;
        *(float4*)((float*)outp + (rb + r)*C_ + c4) = *(const float4*)&os[r*196 + c4];
      }
    } else {
      for (int u = t; u < 384; u += 256){     // 384 u16x8: 24 per row
        int r = u / 24, c8 = (u % 24)*8;
        frag8 o;
        #pragma unroll
        for (int m = 0; m < 8; m++) o.s[m] = (short)f2bf(os[r*196 + c8 + m]);
        *(uint4*)((u16*)outp + (rb + r)*C_ + c8) = o.u4;
      }
    }
    __syncthreads();
  }
}

/* ====================== fallback-path kernels ====================== */

__global__ void prep_biasg(const void* __restrict__ skip, const int* __restrict__ rel,
                           const void* __restrict__ table, u16* __restrict__ biasg){
  const bool F32 = detect_f32((const uint32*)skip);
  int idx = blockIdx.x*256 + threadIdx.x;
  if (idx >= NN_) return;
  int r = rel[idx];
  #pragma unroll
  for (int h = 0; h < H_; h++)
    biasg[(size_t)h*NN_ + idx] = f2bf(ldf(table, (size_t)r*H_ + h, F32));
}

#define KLS_OFF 6400
#define VT_OFF  (KLS_OFF + 352*40)
#define SMEM_U16 (VT_OFF + 32*360)

__global__ __launch_bounds__(512, 4) void attn_fused(
    const void* __restrict__ skip, const void* __restrict__ x_up,
    const void* __restrict__ mask, const u16* __restrict__ biasg,
    const void* __restrict__ kv_w, const void* __restrict__ kv_b,
    void* __restrict__ out){
  __shared__ __align__(16) u16 sm[SMEM_U16];
  const bool F32 = detect_f32((const uint32*)skip);
  const int bid = blockIdx.x;
  const int b = bid / H_, h = bid % H_;
  const int w = b & (NW_-1);
  const int t = threadIdx.x;
  const int lane = t & 63, wave = t >> 6;
  const int n16 = lane & 15, q = lane >> 4;
  const int colt = wave & 3;
  const int half = wave >> 2;
  const int gcol = (colt < 2) ? (h*D_ + colt*16 + n16)
                              : (C_ + h*D_ + (colt-2)*16 + n16);
  const float kvb = ldf(kv_b, gcol, F32);
  frag8 bw[6];
  #pragma unroll
  for (int ks = 0; ks < 6; ks++)
    #pragma unroll
    for (int j = 0; j < 8; j++)
      bw[ks].s[j] = (short)f2bf(ldf(kv_w, (size_t)(ks*32 + q*8 + j)*384 + gcol, F32));

  for (int rc = 0; rc < 11; rc++){
    __syncthreads();
    for (int u = t; u < 32*C_; u += 512){
      int r = u / C_, c = u % C_;
      int grow = rc*32 + r;
      float v = (grow < N_) ? ldf(skip, ((size_t)b*N_ + grow)*C_ + c, F32) : 0.f;
      sm[r*200 + c] = f2bf(v);
    }
    __syncthreads();
    f32x4 acc = {0.f, 0.f, 0.f, 0.f};
    #pragma unroll
    for (int ks = 0; ks < 6; ks++){
      frag8 a;  a.u4 = *(const uint4*)&sm[(half*16 + n16)*200 + ks*32 + q*8];
      acc = __builtin_amdgcn_mfma_f32_16x16x32_bf16(a.h8, bw[ks].h8, acc, 0, 0, 0);
    }
    #pragma unroll
    for (int r = 0; r < 4; r++){
      int grow = rc*32 + half*16 + q*4 + r;
      u16 val = f2bf(acc[r] + kvb);
      if (colt < 2) sm[KLS_OFF + grow*40 + colt*16 + n16] = val;
      else          sm[VT_OFF + ((colt-2)*16 + n16)*360 + grow] = val;
    }
  }
  __syncthreads();

  const float scale = 0.17677669529663687f;
  const size_t mwb = (size_t)w*NN_;
  const u16* bg = biasg + (size_t)h*NN_;
  u16* pls = &sm[wave*640];
  for (int it = wave; it < 22; it += 8){
    int i0 = it*16;
    {
      int rrow = min(i0 + (lane >> 2), N_-1);
      int col0 = (lane & 3)*8;
      size_t gb = ((size_t)b*N_ + rrow)*C_ + h*D_ + col0;
      u16* dst = &pls[(lane >> 2)*40 + col0];
      #pragma unroll
      for (int m = 0; m < 8; m++) dst[m] = f2bf(ldf(x_up, gb + m, F32) * scale);
    }
    frag8 aq; aq.u4 = *(const uint4*)&pls[n16*40 + q*8];
    f32x4 O0 = {0.f,0.f,0.f,0.f}, O1 = {0.f,0.f,0.f,0.f};
    float lp[4] = {0.f, 0.f, 0.f, 0.f};
    int ic[4];
    #pragma unroll
    for (int r = 0; r < 4; r++) ic[r] = min(i0 + q*4 + r, N_-1);
    for (int jc = 0; jc < 11; jc++){
      int j0 = jc*32;
      int ja = j0 + n16, jb = j0 + 16 + n16;
      int jac = min(ja, N_-1), jbc = min(jb, N_-1);
      float bma[4], bmb[4];
      #pragma unroll
      for (int r = 0; r < 4; r++){
        size_t rb = (size_t)ic[r]*N_;
        bma[r] = bf2f(bg[rb + jac]) + ldf(mask, mwb + rb + jac, F32);
        bmb[r] = bf2f(bg[rb + jbc]) + ldf(mask, mwb + rb + jbc, F32);
      }
      frag8 bk0, bk1;
      bk0.u4 = *(const uint4*)&sm[KLS_OFF + (j0 + n16)*40 + q*8];
      bk1.u4 = *(const uint4*)&sm[KLS_OFF + (j0 + 16 + n16)*40 + q*8];
      f32x4 z = {0.f,0.f,0.f,0.f};
      f32x4 s0 = __builtin_amdgcn_mfma_f32_16x16x32_bf16(aq.h8, bk0.h8, z, 0,0,0);
      f32x4 s1 = __builtin_amdgcn_mfma_f32_16x16x32_bf16(aq.h8, bk1.h8, z, 0,0,0);
      #pragma unroll
      for (int r = 0; r < 4; r++){
        float pa = (ja < N_) ? __expf(s0[r] + bma[r] - 12.f) : 0.f;
        float pb = (jb < N_) ? __expf(s1[r] + bmb[r] - 12.f) : 0.f;
        lp[r] += pa + pb;
        pls[(q*4 + r)*40 + n16]      = f2bf(pa);
        pls[(q*4 + r)*40 + 16 + n16] = f2bf(pb);
      }
      frag8 ap; ap.u4 = *(const uint4*)&pls[n16*40 + q*8];
      frag8 bv0, bv1;
      bv0.u4 = *(const uint4*)&sm[VT_OFF + n16*360 + j0 + q*8];
      bv1.u4 = *(const uint4*)&sm[VT_OFF + (16 + n16)*360 + j0 + q*8];
      O0 = __builtin_amdgcn_mfma_f32_16x16x32_bf16(ap.h8, bv0.h8, O0, 0,0,0);
      O1 = __builtin_amdgcn_mfma_f32_16x16x32_bf16(ap.h8, bv1.h8, O1, 0,0,0);
    }
    #pragma unroll
    for (int msk = 1; msk < 16; msk <<= 1){
      #pragma unroll
      for (int r = 0; r < 4; r++) lp[r] += __shfl_xor(lp[r], msk, 64);
    }
    #pragma unroll
    for (int r = 0; r < 4; r++){
      int i = i0 + q*4 + r;
      if (i < N_){
        float rl = 1.f / lp[r];
        size_t ob = ((size_t)b*N_ + i)*C_ + h*D_;
        stf(out, ob + n16,      O0[r]*rl, F32);
        stf(out, ob + 16 + n16, O1[r]*rl, F32);
      }
    }
  }
}

/* ---- in-place projection (tier-B fallback) ---- */
__global__ __launch_bounds__(256, 6) void proj2(void* __restrict__ io,
                                                const void* __restrict__ pw,
                                                const void* __restrict__ pb,
                                                const void* __restrict__ skip){
  __shared__ __align__(16) u16 xs[64*200];   // 25600 B
  const bool F32 = detect_f32((const uint32*)skip);
  const int t = threadIdx.x;
  const int lane = t & 63, wave = t >> 6;
  const int n16 = lane & 15, q = lane >> 4;
  const size_t row0 = (size_t)blockIdx.x * 64;

  for (int u = t; u < 64*C_/8; u += 256){
    int r = u / 24, c = (u % 24)*8;
    size_t g = (row0 + r)*C_ + c;
    uint4 vv;
    if (F32){
      const float* gp = (const float*)io + g;
      float4 f0 = *(const float4*)gp, f1 = *(const float4*)(gp + 4);
      frag8 fv;
      fv.s[0]=(short)f2bf(f0.x); fv.s[1]=(short)f2bf(f0.y);
      fv.s[2]=(short)f2bf(f0.z); fv.s[3]=(short)f2bf(f0.w);
      fv.s[4]=(short)f2bf(f1.x); fv.s[5]=(short)f2bf(f1.y);
      fv.s[6]=(short)f2bf(f1.z); fv.s[7]=(short)f2bf(f1.w);
      vv = fv.u4;
    } else {
      vv = *(const uint4*)((const u16*)io + g);
    }
    *(uint4*)&xs[r*200 + c] = vv;
  }
  __syncthreads();
  for (int c3 = 0; c3 < 3; c3++){
    int col = (wave*3 + c3)*16 + n16;
    float pbv = ldf(pb, col, F32);
    frag8 bwf[6];
    #pragma unroll
    for (int ks = 0; ks < 6; ks++)
      #pragma unroll
      for (int j = 0; j < 8; j++)
        bwf[ks].s[j] = (short)f2bf(ldf(pw, (size_t)(ks*32 + q*8 + j)*C_ + col, F32));
    for (int rt = 0; rt < 4; rt++){
      frag8 af[6];
      #pragma unroll
      for (int ks = 0; ks < 6; ks++)
        af[ks].u4 = *(const uint4*)&xs[(rt*16 + n16)*200 + ks*32 + q*8];
      f32x4 acc = {0.f,0.f,0.f,0.f};
      #pragma unroll
      for (int ks = 0; ks < 6; ks++)
        acc = __builtin_amdgcn_mfma_f32_16x16x32_bf16(af[ks].h8, bwf[ks].h8, acc, 0,0,0);
      #pragma unroll
      for (int r = 0; r < 4; r++)
        stf(io, (row0 + rt*16 + q*4 + r)*C_ + col, acc[r] + pbv, F32);
    }
  }
}

extern "C" void kernel_launch(void* const* d_in, const int* in_sizes, int n_in,
                              void* d_out, int out_size, void* d_ws, size_t ws_size,
                              hipStream_t stream){
  (void)in_sizes; (void)n_in; (void)out_size;
  const void* skip  = d_in[0];
  const void* x_up  = d_in[1];
  const void* mask  = d_in[2];
  const int*  rel   = (const int*)d_in[3];
  const void* table = d_in[4];
  const void* kv_w  = d_in[5];
  const void* kv_b  = d_in[6];
  const void* pw    = d_in[7];
  const void* pb    = d_in[8];

  const size_t PM_BYTES = (size_t)PM_PLANES*PLANE*2;  //  9,416,704
  const size_t KV_BYTES = (size_t)B_*H_*45056;        // 69,206,016
  const size_t XW_BYTES = (size_t)B_*H_*N_*D_*2;      // 33,718,272

  if (ws_size >= PM_BYTES + KV_BYTES + XW_BYTES){
    // Tier A: fused kv(dbuf)+pm -> attn2(xws) -> proj4
    u16* pm   = (u16*)d_ws;
    u16* bpp  = pm;                       // planes 0..5
    u16* msp  = pm + (size_t)H_*PLANE;    // planes 6..37
    u16* kvws = (u16*)((char*)d_ws + PM_BYTES);
    u16* xws  = (u16*)((char*)d_ws + PM_BYTES + KV_BYTES);
    kv_pm<<<B_ + PM_BLKS, 512, 0, stream>>>(skip, kv_w, kv_b, kvws, rel, table, mask, pm);
    attn2<<<B_*H_, 512, 0, stream>>>(skip, x_up, bpp, msp, kvws, xws, d_out);
    proj4<<<87808/64, 256, 0, stream>>>(xws, d_out, pw, pb, skip);
  } else if (ws_size >= PM_BYTES + KV_BYTES){
    // Tier B: no xws -> attn2 writes out, in-place proj
    u16* pm   = (u16*)d_ws;
    u16* bpp  = pm;
    u16* msp  = pm + (size_t)H_*PLANE;
    u16* kvws = (u16*)((char*)d_ws + PM_BYTES);
    kv_pm<<<B_ + PM_BLKS, 512, 0, stream>>>(skip, kv_w, kv_b, kvws, rel, table, mask, pm);
    attn2<<<B_*H_, 512, 0, stream>>>(skip, x_up, bpp, msp, kvws, nullptr, d_out);
    proj2<<<87808/64, 256, 0, stream>>>(d_out, pw, pb, skip);
  } else {
    u16* biasg = (u16*)d_ws;   // 1.41 MB
    prep_biasg<<<(NN_+255)/256, 256, 0, stream>>>(skip, rel, table, biasg);
    attn_fused<<<B_*H_, 512, 0, stream>>>(skip, x_up, mask, biasg, kv_w, kv_b, d_out);
    proj2     <<<87808/64, 256, 0, stream>>>(d_out, pw, pb, skip);
  }
}

// Round 17
// 394.489 us; speedup vs baseline: 1.2145x; 1.0090x over previous
//
#include <hip/hip_runtime.h>
#include <hip/hip_bf16.h>

#define B_  256
#define N_  343
#define C_  192
#define H_  6
#define D_  32
#define NW_ 32
#define NN_ (N_*N_)     /* 117649 */
#define TROWS 2197
#define NP_ 352                    /* padded N */
#define PLANE (NP_*NP_)            /* 123904 u16 per plane */

typedef unsigned int  uint32;
typedef unsigned short u16;
typedef __attribute__((ext_vector_type(8))) short bf16x8;
typedef __attribute__((ext_vector_type(4))) float f32x4;

union frag8 { uint4 u4; bf16x8 h8; short s[8]; };

__device__ __forceinline__ float bf2f(u16 u){
  union { uint32 u; float f; } v; v.u = ((uint32)u) << 16; return v.f;
}
__device__ __forceinline__ u16 f2bf(float f){
  union { float f; uint32 u; } v; v.f = f;
  uint32 u = v.u;
  return (u16)((u + 0x7FFFu + ((u >> 16) & 1u)) >> 16);  // RNE
}

// Deterministic dtype sniff (fp32 vs bf16 input world).
__device__ __forceinline__ bool detect_f32(const uint32* w){
  int c = 0;
  #pragma unroll
  for (int u = 0; u < 32; u++){
    int e = (w[u*37] >> 7) & 0xFF;
    c += (e > 150);
  }
  return c >= 3;
}
__device__ __forceinline__ float ldf(const void* p, size_t i, bool f32){
  return f32 ? ((const float*)p)[i] : bf2f(((const u16*)p)[i]);
}
__device__ __forceinline__ void stf(void* p, size_t i, float v, bool f32){
  if (f32) ((float*)p)[i] = v;
  else     ((u16*)p)[i]   = f2bf(v);
}

// ---- swizzled index helpers (shared by writer + reader => consistency) ----
__device__ __forceinline__ int klsidx(int j, int d){
  return j*32 + ((((d>>3) ^ ((j>>2)&3)))<<3) + (d&7);
}
__device__ __forceinline__ int vtidx(int d, int j){
  return d*352 + ((((j>>3) ^ ((d>>2)&3)))<<3) + (j&7);
}

// packed-plane column decode: packed p = jc*32 + q*8 + half*4 + r  ->  source j
__device__ __forceinline__ int pm_srcj(int p){
  int jc = p >> 5, wi = p & 31;
  return (jc << 5) + ((wi >> 2) & 1)*16 + (wi >> 3)*4 + (wi & 3);
}

// 8 bf16 row-chunk load (zero-pad beyond N_ rows)
__device__ __forceinline__ uint4 ld_row8(const void* __restrict__ src, bool F32,
                                         int b, int grow, int col){
  if (grow >= N_) return make_uint4(0,0,0,0);
  size_t g = ((size_t)b*N_ + grow)*C_ + col;
  if (F32){
    const float* gp = (const float*)src + g;
    float4 f0 = *(const float4*)gp, f1 = *(const float4*)(gp + 4);
    frag8 fv;
    fv.s[0]=(short)f2bf(f0.x); fv.s[1]=(short)f2bf(f0.y);
    fv.s[2]=(short)f2bf(f0.z); fv.s[3]=(short)f2bf(f0.w);
    fv.s[4]=(short)f2bf(f1.x); fv.s[5]=(short)f2bf(f1.y);
    fv.s[6]=(short)f2bf(f1.z); fv.s[7]=(short)f2bf(f1.w);
    return fv.u4;
  }
  return *(const uint4*)((const u16*)src + g);
}

/* ====================== big-ws path kernels ====================== */

#define PM_PLANES (H_ + NW_)   /* 38: bp 6 planes + msp 32 planes */
#define PM_CHUNKS ((size_t)PM_PLANES*PLANE/8)   /* 588544 */
#define PM_BLKS   ((int)((PM_CHUNKS + 511)/512))  /* 1150 */

// Fat kernel: blocks [0,256) = KV GEMM (single-buffer + register prefetch,
// R14-proven); blocks [256,...) = packed split-plane prep (non-interfering).
// Planes stored with PACKED columns (pm_srcj) so attn2 reads both halves of a
// jc as ONE uint4 per plane.
__global__ __launch_bounds__(512, 2) void kv_pm(
    const void* __restrict__ skip, const void* __restrict__ kv_w,
    const void* __restrict__ kv_b, u16* __restrict__ kvws,
    const int* __restrict__ rel, const void* __restrict__ table,
    const void* __restrict__ mask, u16* __restrict__ pm){
  __shared__ __align__(16) u16 sk[32*200];   // 12.8 KB (kv path only)
  const bool F32 = detect_f32((const uint32*)skip);
  const int bx = blockIdx.x;
  const int t = threadIdx.x;

  if (bx >= B_){
    // ---- pm path (packed columns) ----
    const float LOG2E = 1.4426950408889634f;
    size_t chunk = (size_t)(bx - B_)*512 + t;
    if (chunk >= PM_CHUNKS) return;
    size_t gid = chunk*8;
    int p   = (int)(gid / PLANE);
    int rem = (int)(gid % PLANE);
    int i = rem / NP_, p0 = rem % NP_;
    frag8 o;
    if (p < H_){
      #pragma unroll
      for (int m = 0; m < 8; m++){
        int j = pm_srcj(p0 + m); float v = 0.f;
        if (i < N_ && j < N_){
          int r = rel[i*N_ + j];
          v = ldf(table, (size_t)r*H_ + p, F32) * LOG2E;
        }
        o.s[m] = (short)f2bf(v);
      }
    } else {
      int w = p - H_;
      #pragma unroll
      for (int m = 0; m < 8; m++){
        int j = pm_srcj(p0 + m); float v = 0.f;
        if (i < N_ && j < N_)
          v = ldf(mask, (size_t)w*NN_ + (size_t)i*N_ + j, F32) * LOG2E;
        o.s[m] = (short)f2bf(v);
      }
    }
    *(uint4*)&pm[gid] = o.u4;
    return;
  }

  // ---- kv path (b = bx) ----
  const int b = bx;
  const int lane = t & 63, wave = t >> 6;
  const int n16 = lane & 15, q = lane >> 4;

  float kvb[3];
  u16*  p3[3];
  int   d3[3], isK[3];
  frag8 bw[3][6];
  #pragma unroll
  for (int c3 = 0; c3 < 3; c3++){
    int col = (wave*3 + c3)*16 + n16;        // 0..383
    kvb[c3] = ldf(kv_b, col, F32);
    #pragma unroll
    for (int ks = 0; ks < 6; ks++)
      #pragma unroll
      for (int j = 0; j < 8; j++)
        bw[c3][ks].s[j] = (short)f2bf(ldf(kv_w, (size_t)(ks*32 + q*8 + j)*384 + col, F32));
    if (col < 192){
      int h = col >> 5; d3[c3] = col & 31; isK[c3] = 1;
      p3[c3] = kvws + (size_t)(b*H_ + h)*22528;
    } else {
      int cv = col - 192; int h = cv >> 5; d3[c3] = cv & 31; isK[c3] = 0;
      p3[c3] = kvws + (size_t)(b*H_ + h)*22528 + 11264;
    }
  }

  const int r0 = t/24,        c0 = (t%24)*8;
  const int r1 = (t+512)/24,  c1 = ((t+512)%24)*8;
  const bool two = (t < 256);
  uint4 pre0 = ld_row8(skip, F32, b, r0, c0);
  uint4 pre1 = two ? ld_row8(skip, F32, b, r1, c1) : make_uint4(0,0,0,0);

  for (int rc = 0; rc < 11; rc++){
    __syncthreads();
    *(uint4*)&sk[r0*200 + c0] = pre0;
    if (two) *(uint4*)&sk[r1*200 + c1] = pre1;
    __syncthreads();
    if (rc < 10){
      int rb = (rc+1)*32;
      pre0 = ld_row8(skip, F32, b, rb + r0, c0);
      if (two) pre1 = ld_row8(skip, F32, b, rb + r1, c1);
    }
    frag8 af[2][6];
    #pragma unroll
    for (int half = 0; half < 2; half++)
      #pragma unroll
      for (int ks = 0; ks < 6; ks++)
        af[half][ks].u4 = *(const uint4*)&sk[(half*16 + n16)*200 + ks*32 + q*8];
    #pragma unroll
    for (int c3 = 0; c3 < 3; c3++){
      #pragma unroll
      for (int half = 0; half < 2; half++){
        f32x4 acc = {0.f,0.f,0.f,0.f};
        #pragma unroll
        for (int ks = 0; ks < 6; ks++)
          acc = __builtin_amdgcn_mfma_f32_16x16x32_bf16(af[half][ks].h8, bw[c3][ks].h8, acc, 0,0,0);
        #pragma unroll
        for (int r = 0; r < 4; r++){
          int grow = rc*32 + half*16 + q*4 + r;   // up to 351 (finite pad rows kept)
          u16 val = f2bf(acc[r] + kvb[c3]);
          if (isK[c3]) p3[c3][klsidx(grow, d3[c3])] = val;
          else         p3[c3][vtidx(d3[c3], grow)] = val;
        }
      }
    }
  }
}

// ---- attn2 LDS (u16 units): kls 11264 | vT 11264 = 22528 u16 = 45056 B
#define A2_VT  11264
#define A2_TOT 22528

// Swapped-QK^T in-register softmax; bias/mask from packed bp/msp planes:
// ONE uint4 per plane per jc covers both halves. (R14-measured 138 µs config.)
__global__ __launch_bounds__(512, 6) void attn2(
    const void* __restrict__ skip, const void* __restrict__ x_up,
    const u16* __restrict__ bp, const u16* __restrict__ msp,
    const u16* __restrict__ kvws,
    u16* __restrict__ xws, void* __restrict__ out){
  __shared__ __align__(16) u16 sm[A2_TOT];
  const bool F32 = detect_f32((const uint32*)skip);
  const int bid = blockIdx.x;
  const int b = bid / H_, h = bid % H_;
  const int w = b & (NW_-1);
  const int t = threadIdx.x, lane = t & 63, wave = t >> 6;
  const int n16 = lane & 15, q = lane >> 4;

  {
    const uint4* src = (const uint4*)(kvws + (size_t)bid*22528);
    uint4* dst = (uint4*)sm;
    for (int u = t; u < 2816; u += 512) dst[u] = src[u];
  }
  __syncthreads();

  const u16* bpl = bp  + (size_t)h*PLANE;
  const u16* mpl = msp + (size_t)w*PLANE;
  const float SC2 = 0.17677669529663687f * 1.4426950408889634f;  // scale * log2e
  const int src0 = ((q & 1) << 5) + n16;   // shfl sources (loop-invariant)
  const int src1 = src0 + 16;
  const bool lo = (q < 2);

  for (int it = wave; it < 22; it += 8){
    int i0 = it*16;
    const u16* br = bpl + (size_t)(i0 + n16)*NP_ + q*8;   // lane-local packed row
    const u16* mr = mpl + (size_t)(i0 + n16)*NP_ + q*8;
    frag8 aq;   // Q[i=i0+n16][d=q*8..+7] (B-operand of swapped QK^T)
    {
      int qrow = min(i0 + n16, N_-1);
      size_t base = ((size_t)b*N_ + qrow)*C_ + h*D_ + q*8;
      if (F32){
        const float* xf = (const float*)x_up + base;
        float4 f0 = *(const float4*)xf, f1 = *(const float4*)(xf + 4);
        aq.s[0]=(short)f2bf(f0.x); aq.s[1]=(short)f2bf(f0.y);
        aq.s[2]=(short)f2bf(f0.z); aq.s[3]=(short)f2bf(f0.w);
        aq.s[4]=(short)f2bf(f1.x); aq.s[5]=(short)f2bf(f1.y);
        aq.s[6]=(short)f2bf(f1.z); aq.s[7]=(short)f2bf(f1.w);
      } else {
        aq.u4 = *(const uint4*)((const u16*)x_up + base);
      }
    }
    f32x4 O0 = {0.f,0.f,0.f,0.f}, O1 = {0.f,0.f,0.f,0.f};
    float lp = 0.f;                                   // row-i denominator (partial)
    for (int jc = 0; jc < 11; jc++){
      int j0 = jc*32;
      // packed: e[0..3] = half0 (ja), e[4..7] = half1 (jb)
      union U8 { uint4 v; u16 e[8]; } Bv, Mv;
      Bv.v = *(const uint4*)&br[j0];
      Mv.v = *(const uint4*)&mr[j0];
      frag8 bk0, bk1;                                 // K rows as A-operand
      bk0.u4 = *(const uint4*)&sm[klsidx(j0 + n16, q*8)];
      bk1.u4 = *(const uint4*)&sm[klsidx(j0 + 16 + n16, q*8)];
      f32x4 z = {0.f,0.f,0.f,0.f};
      // swapped: D[m=j_local][n=i_local] -> lane holds S[i=i0+n16][j=j0+q*4+r]
      f32x4 s0 = __builtin_amdgcn_mfma_f32_16x16x32_bf16(bk0.h8, aq.h8, z, 0,0,0);
      f32x4 s1 = __builtin_amdgcn_mfma_f32_16x16x32_bf16(bk1.h8, aq.h8, z, 0,0,0);
      float pa[4], pb[4];
      if (jc < 10){                                   // no masking needed (j <= 335)
        #pragma unroll
        for (int r = 0; r < 4; r++){
          pa[r] = exp2f(fmaf(s0[r], SC2, bf2f(Bv.e[r])   + bf2f(Mv.e[r])));
          pb[r] = exp2f(fmaf(s1[r], SC2, bf2f(Bv.e[4+r]) + bf2f(Mv.e[4+r])));
          lp += pa[r] + pb[r];
        }
      } else {                                        // jc=10: mask j>=343 in pb
        #pragma unroll
        for (int r = 0; r < 4; r++){
          pa[r] = exp2f(fmaf(s0[r], SC2, bf2f(Bv.e[r]) + bf2f(Mv.e[r])));
          float eb = exp2f(fmaf(s1[r], SC2, bf2f(Bv.e[4+r]) + bf2f(Mv.e[4+r])));
          pb[r] = (336 + q*4 + r < N_) ? eb : 0.f;
          lp += pa[r] + pb[r];
        }
      }
      // P -> bf16 pairs (lane-local row), then redistribute to PV A-frag layout
      uint32 A0, A1, B0, B1;
      asm("v_cvt_pk_bf16_f32 %0, %1, %2" : "=v"(A0) : "v"(pa[0]), "v"(pa[1]));
      asm("v_cvt_pk_bf16_f32 %0, %1, %2" : "=v"(A1) : "v"(pa[2]), "v"(pa[3]));
      asm("v_cvt_pk_bf16_f32 %0, %1, %2" : "=v"(B0) : "v"(pb[0]), "v"(pb[1]));
      asm("v_cvt_pk_bf16_f32 %0, %1, %2" : "=v"(B1) : "v"(pb[2]), "v"(pb[3]));
      // target (q,n16) needs P[i=n16][j=q*8..+7]: sources lanes (q&1)*32+n16, +16
      uint32 a0s = (uint32)__shfl((int)A0, src0), a1s = (uint32)__shfl((int)A1, src0);
      uint32 a2s = (uint32)__shfl((int)A0, src1), a3s = (uint32)__shfl((int)A1, src1);
      uint32 b0s = (uint32)__shfl((int)B0, src0), b1s = (uint32)__shfl((int)B1, src0);
      uint32 b2s = (uint32)__shfl((int)B0, src1), b3s = (uint32)__shfl((int)B1, src1);
      frag8 ap;
      ap.u4.x = lo ? a0s : b0s;
      ap.u4.y = lo ? a1s : b1s;
      ap.u4.z = lo ? a2s : b2s;
      ap.u4.w = lo ? a3s : b3s;
      frag8 bv0, bv1;
      bv0.u4 = *(const uint4*)&sm[A2_VT + vtidx(n16,      j0 + q*8)];
      bv1.u4 = *(const uint4*)&sm[A2_VT + vtidx(16 + n16, j0 + q*8)];
      O0 = __builtin_amdgcn_mfma_f32_16x16x32_bf16(ap.h8, bv0.h8, O0, 0,0,0);
      O1 = __builtin_amdgcn_mfma_f32_16x16x32_bf16(ap.h8, bv1.h8, O1, 0,0,0);
    }
    // full denominator for row i0+n16 (q-groups hold disjoint j's)
    lp += __shfl_xor(lp, 16);
    lp += __shfl_xor(lp, 32);
    #pragma unroll
    for (int r = 0; r < 4; r++){
      int il = q*4 + r;
      float rl = 1.f / __shfl(lp, (lane & 48) | il);   // lsum lives at n16 == il
      int i = i0 + il;
      if (i < N_){
        if (xws){
          u16* xp = xws + ((size_t)(b*H_ + h)*N_ + i)*D_;
          xp[n16]      = f2bf(O0[r]*rl);
          xp[16 + n16] = f2bf(O1[r]*rl);
        } else {
          size_t ob = ((size_t)b*N_ + i)*C_ + h*D_;
          stf(out, ob + n16,      O0[r]*rl, F32);
          stf(out, ob + 16 + n16, O1[r]*rl, F32);
        }
      }
    }
  }
}

// proj4: read bf16 xws, write d_out ONCE via LDS-staged full-line vector stores.
__global__ __launch_bounds__(256, 4) void proj4(const u16* __restrict__ xws,
                                                void* __restrict__ outp,
                                                const void* __restrict__ pw,
                                                const void* __restrict__ pb,
                                                const void* __restrict__ skip){
  __shared__ __align__(16) u16 xs[64*200];     // 25600 B
  __shared__ __align__(16) float os[16*196];   // 12544 B (pad 196 breaks q-bank aliasing)
  const bool F32 = detect_f32((const uint32*)skip);
  const int t = threadIdx.x, lane = t & 63, wave = t >> 6;
  const int n16 = lane & 15, q = lane >> 4;
  const size_t row0 = (size_t)blockIdx.x * 64;

  for (int u = t; u < 1536; u += 256){
    int r = u / 24, c8 = u % 24;
    int g = (int)row0 + r;
    int b = g / N_, i = g - b*N_;
    int h = c8 >> 2, d0 = (c8 & 3)*8;
    uint4 vv = *(const uint4*)&xws[((size_t)(b*H_ + h)*N_ + i)*D_ + d0];
    *(uint4*)&xs[r*200 + h*32 + d0] = vv;
  }
  frag8 bwf[3][6];
  float pbv[3];
  #pragma unroll
  for (int c3 = 0; c3 < 3; c3++){
    int col = (wave*3 + c3)*16 + n16;
    pbv[c3] = ldf(pb, col, F32);
    #pragma unroll
    for (int ks = 0; ks < 6; ks++)
      #pragma unroll
      for (int j = 0; j < 8; j++)
        bwf[c3][ks].s[j] = (short)f2bf(ldf(pw, (size_t)(ks*32 + q*8 + j)*C_ + col, F32));
  }
  __syncthreads();
  for (int rt = 0; rt < 4; rt++){
    frag8 af[6];
    #pragma unroll
    for (int ks = 0; ks < 6; ks++)
      af[ks].u4 = *(const uint4*)&xs[(rt*16 + n16)*200 + ks*32 + q*8];
    #pragma unroll
    for (int c3 = 0; c3 < 3; c3++){
      f32x4 acc = {0.f,0.f,0.f,0.f};
      #pragma unroll
      for (int ks = 0; ks < 6; ks++)
        acc = __builtin_amdgcn_mfma_f32_16x16x32_bf16(af[ks].h8, bwf[c3][ks].h8, acc, 0,0,0);
      int col = (wave*3 + c3)*16 + n16;
      #pragma unroll
      for (int r = 0; r < 4; r++)
        os[(q*4 + r)*196 + col] = acc[r] + pbv[c3];
    }
    __syncthreads();
    size_t rb = row0 + rt*16;
    if (F32){
      for (int u = t; u < 768; u += 256){     // 768 float4: 48 per row
        int r = u / 48, c4 = (u % 48)*4;
        *(float4*)((float*)outp + (rb + r)*C_ + c4) = *(const float4*)&os[r*196 + c4];
      }
    } else {
      for (int u = t; u < 384; u += 256){     // 384 u16x8: 24 per row
        int r = u / 24, c8 = (u % 24)*8;
        frag8 o;
        #pragma unroll
        for (int m = 0; m < 8; m++) o.s[m] = (short)f2bf(os[r*196 + c8 + m]);
        *(uint4*)((u16*)outp + (rb + r)*C_ + c8) = o.u4;
      }
    }
    __syncthreads();
  }
}

/* ====================== fallback-path kernels ====================== */

__global__ void prep_biasg(const void* __restrict__ skip, const int* __restrict__ rel,
                           const void* __restrict__ table, u16* __restrict__ biasg){
  const bool F32 = detect_f32((const uint32*)skip);
  int idx = blockIdx.x*256 + threadIdx.x;
  if (idx >= NN_) return;
  int r = rel[idx];
  #pragma unroll
  for (int h = 0; h < H_; h++)
    biasg[(size_t)h*NN_ + idx] = f2bf(ldf(table, (size_t)r*H_ + h, F32));
}

#define KLS_OFF 6400
#define VT_OFF  (KLS_OFF + 352*40)
#define SMEM_U16 (VT_OFF + 32*360)

__global__ __launch_bounds__(512, 4) void attn_fused(
    const void* __restrict__ skip, const void* __restrict__ x_up,
    const void* __restrict__ mask, const u16* __restrict__ biasg,
    const void* __restrict__ kv_w, const void* __restrict__ kv_b,
    void* __restrict__ out){
  __shared__ __align__(16) u16 sm[SMEM_U16];
  const bool F32 = detect_f32((const uint32*)skip);
  const int bid = blockIdx.x;
  const int b = bid / H_, h = bid % H_;
  const int w = b & (NW_-1);
  const int t = threadIdx.x;
  const int lane = t & 63, wave = t >> 6;
  const int n16 = lane & 15, q = lane >> 4;
  const int colt = wave & 3;
  const int half = wave >> 2;
  const int gcol = (colt < 2) ? (h*D_ + colt*16 + n16)
                              : (C_ + h*D_ + (colt-2)*16 + n16);
  const float kvb = ldf(kv_b, gcol, F32);
  frag8 bw[6];
  #pragma unroll
  for (int ks = 0; ks < 6; ks++)
    #pragma unroll
    for (int j = 0; j < 8; j++)
      bw[ks].s[j] = (short)f2bf(ldf(kv_w, (size_t)(ks*32 + q*8 + j)*384 + gcol, F32));

  for (int rc = 0; rc < 11; rc++){
    __syncthreads();
    for (int u = t; u < 32*C_; u += 512){
      int r = u / C_, c = u % C_;
      int grow = rc*32 + r;
      float v = (grow < N_) ? ldf(skip, ((size_t)b*N_ + grow)*C_ + c, F32) : 0.f;
      sm[r*200 + c] = f2bf(v);
    }
    __syncthreads();
    f32x4 acc = {0.f, 0.f, 0.f, 0.f};
    #pragma unroll
    for (int ks = 0; ks < 6; ks++){
      frag8 a;  a.u4 = *(const uint4*)&sm[(half*16 + n16)*200 + ks*32 + q*8];
      acc = __builtin_amdgcn_mfma_f32_16x16x32_bf16(a.h8, bw[ks].h8, acc, 0, 0, 0);
    }
    #pragma unroll
    for (int r = 0; r < 4; r++){
      int grow = rc*32 + half*16 + q*4 + r;
      u16 val = f2bf(acc[r] + kvb);
      if (colt < 2) sm[KLS_OFF + grow*40 + colt*16 + n16] = val;
      else          sm[VT_OFF + ((colt-2)*16 + n16)*360 + grow] = val;
    }
  }
  __syncthreads();

  const float scale = 0.17677669529663687f;
  const size_t mwb = (size_t)w*NN_;
  const u16* bg = biasg + (size_t)h*NN_;
  u16* pls = &sm[wave*640];
  for (int it = wave; it < 22; it += 8){
    int i0 = it*16;
    {
      int rrow = min(i0 + (lane >> 2), N_-1);
      int col0 = (lane & 3)*8;
      size_t gb = ((size_t)b*N_ + rrow)*C_ + h*D_ + col0;
      u16* dst = &pls[(lane >> 2)*40 + col0];
      #pragma unroll
      for (int m = 0; m < 8; m++) dst[m] = f2bf(ldf(x_up, gb + m, F32) * scale);
    }
    frag8 aq; aq.u4 = *(const uint4*)&pls[n16*40 + q*8];
    f32x4 O0 = {0.f,0.f,0.f,0.f}, O1 = {0.f,0.f,0.f,0.f};
    float lp[4] = {0.f, 0.f, 0.f, 0.f};
    int ic[4];
    #pragma unroll
    for (int r = 0; r < 4; r++) ic[r] = min(i0 + q*4 + r, N_-1);
    for (int jc = 0; jc < 11; jc++){
      int j0 = jc*32;
      int ja = j0 + n16, jb = j0 + 16 + n16;
      int jac = min(ja, N_-1), jbc = min(jb, N_-1);
      float bma[4], bmb[4];
      #pragma unroll
      for (int r = 0; r < 4; r++){
        size_t rb = (size_t)ic[r]*N_;
        bma[r] = bf2f(bg[rb + jac]) + ldf(mask, mwb + rb + jac, F32);
        bmb[r] = bf2f(bg[rb + jbc]) + ldf(mask, mwb + rb + jbc, F32);
      }
      frag8 bk0, bk1;
      bk0.u4 = *(const uint4*)&sm[KLS_OFF + (j0 + n16)*40 + q*8];
      bk1.u4 = *(const uint4*)&sm[KLS_OFF + (j0 + 16 + n16)*40 + q*8];
      f32x4 z = {0.f,0.f,0.f,0.f};
      f32x4 s0 = __builtin_amdgcn_mfma_f32_16x16x32_bf16(aq.h8, bk0.h8, z, 0,0,0);
      f32x4 s1 = __builtin_amdgcn_mfma_f32_16x16x32_bf16(aq.h8, bk1.h8, z, 0,0,0);
      #pragma unroll
      for (int r = 0; r < 4; r++){
        float pa = (ja < N_) ? __expf(s0[r] + bma[r] - 12.f) : 0.f;
        float pb = (jb < N_) ? __expf(s1[r] + bmb[r] - 12.f) : 0.f;
        lp[r] += pa + pb;
        pls[(q*4 + r)*40 + n16]      = f2bf(pa);
        pls[(q*4 + r)*40 + 16 + n16] = f2bf(pb);
      }
      frag8 ap; ap.u4 = *(const uint4*)&pls[n16*40 + q*8];
      frag8 bv0, bv1;
      bv0.u4 = *(const uint4*)&sm[VT_OFF + n16*360 + j0 + q*8];
      bv1.u4 = *(const uint4*)&sm[VT_OFF + (16 + n16)*360 + j0 + q*8];
      O0 = __builtin_amdgcn_mfma_f32_16x16x32_bf16(ap.h8, bv0.h8, O0, 0,0,0);
      O1 = __builtin_amdgcn_mfma_f32_16x16x32_bf16(ap.h8, bv1.h8, O1, 0,0,0);
    }
    #pragma unroll
    for (int msk = 1; msk < 16; msk <<= 1){
      #pragma unroll
      for (int r = 0; r < 4; r++) lp[r] += __shfl_xor(lp[r], msk, 64);
    }
    #pragma unroll
    for (int r = 0; r < 4; r++){
      int i = i0 + q*4 + r;
      if (i < N_){
        float rl = 1.f / lp[r];
        size_t ob = ((size_t)b*N_ + i)*C_ + h*D_;
        stf(out, ob + n16,      O0[r]*rl, F32);
        stf(out, ob + 16 + n16, O1[r]*rl, F32);
      }
    }
  }
}

/* ---- in-place projection (tier-B fallback) ---- */
__global__ __launch_bounds__(256, 6) void proj2(void* __restrict__ io,
                                                const void* __restrict__ pw,
                                                const void* __restrict__ pb,
                                                const void* __restrict__ skip){
  __shared__ __align__(16) u16 xs[64*200];   // 25600 B
  const bool F32 = detect_f32((const uint32*)skip);
  const int t = threadIdx.x;
  const int lane = t & 63, wave = t >> 6;
  const int n16 = lane & 15, q = lane >> 4;
  const size_t row0 = (size_t)blockIdx.x * 64;

  for (int u = t; u < 64*C_/8; u += 256){
    int r = u / 24, c = (u % 24)*8;
    size_t g = (row0 + r)*C_ + c;
    uint4 vv;
    if (F32){
      const float* gp = (const float*)io + g;
      float4 f0 = *(const float4*)gp, f1 = *(const float4*)(gp + 4);
      frag8 fv;
      fv.s[0]=(short)f2bf(f0.x); fv.s[1]=(short)f2bf(f0.y);
      fv.s[2]=(short)f2bf(f0.z); fv.s[3]=(short)f2bf(f0.w);
      fv.s[4]=(short)f2bf(f1.x); fv.s[5]=(short)f2bf(f1.y);
      fv.s[6]=(short)f2bf(f1.z); fv.s[7]=(short)f2bf(f1.w);
      vv = fv.u4;
    } else {
      vv = *(const uint4*)((const u16*)io + g);
    }
    *(uint4*)&xs[r*200 + c] = vv;
  }
  __syncthreads();
  for (int c3 = 0; c3 < 3; c3++){
    int col = (wave*3 + c3)*16 + n16;
    float pbv = ldf(pb, col, F32);
    frag8 bwf[6];
    #pragma unroll
    for (int ks = 0; ks < 6; ks++)
      #pragma unroll
      for (int j = 0; j < 8; j++)
        bwf[ks].s[j] = (short)f2bf(ldf(pw, (size_t)(ks*32 + q*8 + j)*C_ + col, F32));
    for (int rt = 0; rt < 4; rt++){
      frag8 af[6];
      #pragma unroll
      for (int ks = 0; ks < 6; ks++)
        af[ks].u4 = *(const uint4*)&xs[(rt*16 + n16)*200 + ks*32 + q*8];
      f32x4 acc = {0.f,0.f,0.f,0.f};
      #pragma unroll
      for (int ks = 0; ks < 6; ks++)
        acc = __builtin_amdgcn_mfma_f32_16x16x32_bf16(af[ks].h8, bwf[ks].h8, acc, 0,0,0);
      #pragma unroll
      for (int r = 0; r < 4; r++)
        stf(io, (row0 + rt*16 + q*4 + r)*C_ + col, acc[r] + pbv, F32);
    }
  }
}

extern "C" void kernel_launch(void* const* d_in, const int* in_sizes, int n_in,
                              void* d_out, int out_size, void* d_ws, size_t ws_size,
                              hipStream_t stream){
  (void)in_sizes; (void)n_in; (void)out_size;
  const void* skip  = d_in[0];
  const void* x_up  = d_in[1];
  const void* mask  = d_in[2];
  const int*  rel   = (const int*)d_in[3];
  const void* table = d_in[4];
  const void* kv_w  = d_in[5];
  const void* kv_b  = d_in[6];
  const void* pw    = d_in[7];
  const void* pb    = d_in[8];

  const size_t PM_BYTES = (size_t)PM_PLANES*PLANE*2;  //  9,416,704
  const size_t KV_BYTES = (size_t)B_*H_*45056;        // 69,206,016
  const size_t XW_BYTES = (size_t)B_*H_*N_*D_*2;      // 33,718,272

  if (ws_size >= PM_BYTES + KV_BYTES + XW_BYTES){
    // Tier A: fused kv+pm (packed planes) -> attn2(xws) -> proj4
    u16* pm   = (u16*)d_ws;
    u16* bpp  = pm;                       // planes 0..5
    u16* msp  = pm + (size_t)H_*PLANE;    // planes 6..37
    u16* kvws = (u16*)((char*)d_ws + PM_BYTES);
    u16* xws  = (u16*)((char*)d_ws + PM_BYTES + KV_BYTES);
    kv_pm<<<B_ + PM_BLKS, 512, 0, stream>>>(skip, kv_w, kv_b, kvws, rel, table, mask, pm);
    attn2<<<B_*H_, 512, 0, stream>>>(skip, x_up, bpp, msp, kvws, xws, d_out);
    proj4<<<87808/64, 256, 0, stream>>>(xws, d_out, pw, pb, skip);
  } else if (ws_size >= PM_BYTES + KV_BYTES){
    // Tier B: no xws -> attn2 writes out, in-place proj
    u16* pm   = (u16*)d_ws;
    u16* bpp  = pm;
    u16* msp  = pm + (size_t)H_*PLANE;
    u16* kvws = (u16*)((char*)d_ws + PM_BYTES);
    kv_pm<<<B_ + PM_BLKS, 512, 0, stream>>>(skip, kv_w, kv_b, kvws, rel, table, mask, pm);
    attn2<<<B_*H_, 512, 0, stream>>>(skip, x_up, bpp, msp, kvws, nullptr, d_out);
    proj2<<<87808/64, 256, 0, stream>>>(d_out, pw, pb, skip);
  } else {
    u16* biasg = (u16*)d_ws;   // 1.41 MB
    prep_biasg<<<(NN_+255)/256, 256, 0, stream>>>(skip, rel, table, biasg);
    attn_fused<<<B_*H_, 512, 0, stream>>>(skip, x_up, mask, biasg, kv_w, kv_b, d_out);
    proj2     <<<87808/64, 256, 0, stream>>>(d_out, pw, pb, skip);
  }
}